// Round 1
// baseline (305.459 us; speedup 1.0000x reference)
//
#include <hip/hip_runtime.h>

typedef float f32x4  __attribute__((ext_vector_type(4)));
typedef float f32x16 __attribute__((ext_vector_type(16)));
typedef short s16x8  __attribute__((ext_vector_type(8)));

constexpr int NL  = 31;
constexpr int BB  = 64;
constexpr int TT  = 512;
constexpr int DD  = 768;
constexpr int RTOT = BB * TT;
constexpr int IDX_EOS = 29;
constexpr int IDX_BOS = 30;
constexpr float LOG2E = 1.4426950408889634f;
constexpr float LN2F  = 0.6931471805599453f;

union Frag8 { unsigned u[4]; s16x8 s; };

__device__ inline unsigned pk2(float a, float b) {
  unsigned ua = __float_as_uint(a), ub = __float_as_uint(b);
  ua = (ua + 0x7fffu + ((ua >> 16) & 1u)) >> 16;   // RNE f32->bf16
  ub = (ub + 0x7fffu + ((ub >> 16) & 1u)) >> 16;
  return ua | (ub << 16);
}
__device__ inline unsigned short bf16r(float a) {
  unsigned ua = __float_as_uint(a);
  return (unsigned short)((ua + 0x7fffu + ((ua >> 16) & 1u)) >> 16);
}

__device__ inline float bfly_max32(float v) {
#define STEPM(K) { float o = __int_as_float(__builtin_amdgcn_ds_swizzle(__float_as_int(v), ((K) << 10) | 0x1f)); v = fmaxf(v, o); }
  STEPM(1) STEPM(2) STEPM(4) STEPM(8) STEPM(16)
#undef STEPM
  return v;
}
__device__ inline float bfly_sum32(float v) {
#define STEPS(K) { float o = __int_as_float(__builtin_amdgcn_ds_swizzle(__float_as_int(v), ((K) << 10) | 0x1f)); v = v + o; }
  STEPS(1) STEPS(2) STEPS(4) STEPS(8) STEPS(16)
#undef STEPS
  return v;
}

// D(C-layout, f32[16]) -> B-frag(bf16) half-swap repack [R2-verified]
__device__ inline void repack(const float E[16], int h, Frag8& B1, Frag8& B2) {
  unsigned o1a = pk2(E[4 * h], E[4 * h + 1]), o1b = pk2(E[4 * h + 2], E[4 * h + 3]);
  unsigned o2a = pk2(E[8 + 4 * h], E[8 + 4 * h + 1]), o2b = pk2(E[8 + 4 * h + 2], E[8 + 4 * h + 3]);
  int hb = 4 * (1 - h);
  unsigned s1a = pk2(E[hb], E[hb + 1]),         s1b = pk2(E[hb + 2], E[hb + 3]);
  unsigned s2a = pk2(E[8 + hb], E[8 + hb + 1]), s2b = pk2(E[8 + hb + 2], E[8 + hb + 3]);
  unsigned r1a = __shfl_xor((int)s1a, 32), r1b = __shfl_xor((int)s1b, 32);
  unsigned r2a = __shfl_xor((int)s2a, 32), r2b = __shfl_xor((int)s2b, 32);
  if (h == 0) {
    B1.u[0] = o1a; B1.u[1] = o1b; B1.u[2] = r1a; B1.u[3] = r1b;
    B2.u[0] = o2a; B2.u[1] = o2b; B2.u[2] = r2a; B2.u[3] = r2b;
  } else {
    B1.u[0] = r1a; B1.u[1] = r1b; B1.u[2] = o1a; B1.u[3] = o1b;
    B2.u[0] = r2a; B2.u[1] = r2b; B2.u[2] = o2a; B2.u[3] = o2b;
  }
}

__device__ inline void renorm16(float E[16], float& Sacc) {
  float m = E[0];
#pragma unroll
  for (int r = 1; r < 16; ++r) m = fmaxf(m, E[r]);
  m = bfly_max32(m);
  m = fmaxf(m, __shfl_xor(m, 32));
  float lg = truncf(log2f(m));
  Sacc += lg;
  float sc = exp2f(-lg);
#pragma unroll
  for (int r = 0; r < 16; ++r) E[r] *= sc;
}

// bf16 row-major 32x32 matrix -> A-frags (A[m][k], m = lane&31)
__device__ inline void load_A16(const unsigned short* M, int l, int h, Frag8& A1, Frag8& A2) {
  A1.s = *(const s16x8*)(M + l * 32 + 8 * h);
  A2.s = *(const s16x8*)(M + l * 32 + 16 + 8 * h);
}
// bf16 row-major 32x32 matrix -> B-frags (B[k][n], n = lane&31)
__device__ inline void load_B16(const unsigned short* M, int l, int h, Frag8& B1, Frag8& B2) {
#pragma unroll
  for (int m = 0; m < 4; ++m) {
    int k = 8 * h + 2 * m;
    unsigned lo0 = M[k * 32 + l],        hi0 = M[(k + 1) * 32 + l];
    unsigned lo1 = M[(k + 16) * 32 + l], hi1 = M[(k + 17) * 32 + l];
    B1.u[m] = lo0 | (hi0 << 16);
    B2.u[m] = lo1 | (hi1 << 16);
  }
}

// ------------- K0: state_w -> bf16 padded ----------------------------------
__global__ void k_prep(const float* __restrict__ sw, unsigned short* __restrict__ Bw) {
  for (int i = blockIdx.x * 256 + threadIdx.x; i < 32 * DD; i += 8 * 256)
    Bw[i] = (i < NL * DD) ? bf16r(sw[i]) : (unsigned short)0;
}

// ------------- K1 fused: out_s GEMM + energy write + tgt-energy partial -----
// Each block owns 64 rows: computes outs tile (MFMA, wave-private LDS staging,
// no barriers in GEMM phase), keeps the tile in LDS, then streams the 64x961
// energy block directly (overlaps the 126MB write with the 101MB input read)
// and emits its tgt-energy partial (no atomics, no pre-zero needed).
__global__ __launch_bounds__(256) void k_outs(
    const float* __restrict__ inp, const unsigned short* __restrict__ Bw,
    const float* __restrict__ sb, const float* __restrict__ msk,
    const float* __restrict__ trans, const int* __restrict__ target,
    float* __restrict__ outs, float* __restrict__ energy,
    float* __restrict__ ws_partial)
{
  __shared__ __align__(16) unsigned short As[4][16 * 72];  // stride 72: 2-way banks (free)
  __shared__ float tr[961];
  __shared__ float osh[64 * NL];
  int tid = threadIdx.x, wave = tid >> 6, lane = tid & 63;
  int quad = lane >> 4, l15 = lane & 15;
  int r0 = blockIdx.x * 64;
  int rw = r0 + wave * 16;

  // trans -> LDS (drained by the __syncthreads below)
  for (int idx = tid; idx < 961; idx += 256) tr[idx] = trans[idx];

  int srow = lane >> 2, scol = lane & 3;      // staging: 4 lanes per row
  const float* gsrc = inp + (size_t)(rw + srow) * DD + scol * 4;
  unsigned short* asb = As[wave];
  unsigned* dw = (unsigned*)asb;
  int wbase = srow * 36 + scol * 2;

  f32x4 pre[4];
#pragma unroll
  for (int i = 0; i < 4; ++i) pre[i] = *(const f32x4*)(gsrc + i * 16);

  f32x4 acc[2] = {};
  for (int kc = 0; kc < 12; ++kc) {
#pragma unroll
    for (int i = 0; i < 4; ++i) {
      dw[wbase + i * 8]     = pk2(pre[i][0], pre[i][1]);
      dw[wbase + i * 8 + 1] = pk2(pre[i][2], pre[i][3]);
    }
    if (kc < 11) {
      const float* g2 = gsrc + (kc + 1) * 64;
#pragma unroll
      for (int i = 0; i < 4; ++i) pre[i] = *(const f32x4*)(g2 + i * 16);
    }
#pragma unroll
    for (int ks = 0; ks < 2; ++ks) {
      s16x8 af = *(const s16x8*)(asb + l15 * 72 + ks * 32 + quad * 8);
#pragma unroll
      for (int ct = 0; ct < 2; ++ct) {
        s16x8 bf = *(const s16x8*)(Bw + (ct * 16 + l15) * DD + kc * 64 + ks * 32 + quad * 8);
        acc[ct] = __builtin_amdgcn_mfma_f32_16x16x32_bf16(af, bf, acc[ct], 0, 0, 0);
      }
    }
  }
  // epilogue: bias + mask, park tile in LDS + global outs
#pragma unroll
  for (int ct = 0; ct < 2; ++ct) {
    int n = ct * 16 + l15;
    if (n >= NL) continue;
    float b = sb[n];
#pragma unroll
    for (int r = 0; r < 4; ++r) {
      int lr = wave * 16 + quad * 4 + r;
      int row = r0 + lr;
      float v = acc[ct][r] + b;
      if (n == IDX_EOS && msk[row] == 0.f) v += 20000.f;
      osh[lr * NL + n] = v;
      outs[(size_t)row * NL + n] = v;
    }
  }
  __syncthreads();

  // tgt-energy partial for this block's 64 rows
  if (tid < 64) {
    int r = r0 + tid;
    int tg = target[r];
    int prv = ((r & (TT - 1)) == 0) ? IDX_BOS : target[r - 1];
    float cc = tr[prv * NL + tg] + osh[tid * NL + tg];
#pragma unroll
    for (int off = 32; off; off >>= 1) cc += __shfl_down(cc, off);
    if (tid == 0) ws_partial[blockIdx.x] = cc;
  }

  // energy: 64*961 = 61504 f32 = 15376 vec4 (base 16B-aligned)
  float* dst = energy + (size_t)r0 * 961;
#pragma unroll 4
  for (int it = 0; it < 60; ++it) {
    int v = it * 256 + tid;
    int e = v * 4;
    f32x4 val;
#pragma unroll
    for (int k = 0; k < 4; ++k) {
      unsigned x = e + k;
      unsigned q = __umulhi(x, 4469269u);        // x / 961 (exact, x < 20M)
      unsigned c = x - q * 961u;
      unsigned j = c - 31u * ((c * 67651u) >> 21); // c % 31 (exact, c < 961)
      val[k] = tr[c] + osh[q * NL + j];
    }
    *(f32x4*)(dst + e) = val;
  }
  if (tid < 16) {
    int e = (15360 + tid) * 4;
    f32x4 val;
#pragma unroll
    for (int k = 0; k < 4; ++k) {
      unsigned x = e + k;
      unsigned q = __umulhi(x, 4469269u);
      unsigned c = x - q * 961u;
      unsigned j = c - 31u * ((c * 67651u) >> 21);
      val[k] = tr[c] + osh[q * NL + j];
    }
    *(f32x4*)(dst + e) = val;
  }
}

// ------------- K2 fused: 8-step seg matrices + in-block quad product --------
// 4 waves/block = 4 consecutive same-batch units; quad product M3*M2*M1*M0
// done in-LDS (was k_tree1), so Mseg16 never touches global memory.
__global__ __launch_bounds__(256) void k_seg(
    const float* __restrict__ outs, const float* __restrict__ trans,
    unsigned short* __restrict__ Mq16, float* __restrict__ Sq)
{
  __shared__ float ub4[4][256];
  __shared__ __align__(16) unsigned short Ms[4][1024];
  __shared__ float Ss[4];
  int tid = threadIdx.x, wave = tid >> 6, lane = tid & 63;
  int l = lane & 31, h = lane >> 5;
  int unit = blockIdx.x * 4 + wave;
  int b = unit >> 6, c = unit & 63;
  int t0 = 1 + c * 8;
  int n = (c == 63) ? 7 : 8;

  float* ub = ub4[wave];
#pragma unroll
  for (int it = 0; it < 4; ++it) {
    int idx = lane + it * 64;
    int row = idx >> 5, col = idx & 31;
    float v = 0.f;
    if (col < NL && row < n)
      v = exp2f(LOG2E * outs[((size_t)b * TT + t0 + row) * NL + col]);
    ub[idx] = v;
  }

  Frag8 A1, A2, B1, B2;
#pragma unroll
  for (int m = 0; m < 4; ++m) {
    int k0 = 8 * h + 2 * m, k1 = k0 + 1;
    float a0 = (k0 < NL && l < NL) ? exp2f(LOG2E * trans[k0 * NL + l]) : 0.f;
    float a1 = (k1 < NL && l < NL) ? exp2f(LOG2E * trans[k1 * NL + l]) : 0.f;
    A1.u[m] = pk2(a0, a1);
    int k2 = 16 + k0, k3 = 16 + k1;
    float a2 = (k2 < NL && l < NL) ? exp2f(LOG2E * trans[k2 * NL + l]) : 0.f;
    float a3 = (k3 < NL && l < NL) ? exp2f(LOG2E * trans[k3 * NL + l]) : 0.f;
    A2.u[m] = pk2(a2, a3);
    B1.u[m] = ((k0 == l) ? 0x3f80u : 0u) | (((k1 == l) ? 0x3f80u : 0u) << 16);
    B2.u[m] = ((k2 == l) ? 0x3f80u : 0u) | (((k3 == l) ? 0x3f80u : 0u) << 16);
  }

  float E[16];
  for (int s = 0; s < n; ++s) {
    const float* us = ub + s * 32 + 4 * h;
    f32x4 u0 = *(const f32x4*)(us);
    f32x4 u1 = *(const f32x4*)(us + 8);
    f32x4 u2 = *(const f32x4*)(us + 16);
    f32x4 u3 = *(const f32x4*)(us + 24);
    f32x16 D = {};
    D = __builtin_amdgcn_mfma_f32_32x32x16_bf16(A1.s, B1.s, D, 0, 0, 0);
    D = __builtin_amdgcn_mfma_f32_32x32x16_bf16(A2.s, B2.s, D, 0, 0, 0);
#pragma unroll
    for (int jj = 0; jj < 4; ++jj) {
      E[jj]      = D[jj]      * u0[jj];
      E[4 + jj]  = D[4 + jj]  * u1[jj];
      E[8 + jj]  = D[8 + jj]  * u2[jj];
      E[12 + jj] = D[12 + jj] * u3[jj];
    }
    if (s + 1 < n) repack(E, h, B1, B2);
  }
  float S = 0.f;
  renorm16(E, S);
  unsigned short* mo = Ms[wave];
#pragma unroll
  for (int r = 0; r < 16; ++r) {
    int row = (r & 3) + 8 * (r >> 2) + 4 * h;
    mo[row * 32 + l] = bf16r(E[r]);
  }
  if (lane == 0) Ss[wave] = S;
  __syncthreads();

  if (wave == 0) {
    // quad product Q = M3*M2*M1*M0 (was k_tree1), one wave, in LDS
    load_B16(Ms[0], l, h, B1, B2);
    float Sx = Ss[0] + Ss[1] + Ss[2] + Ss[3];
    float E2[16];
#pragma unroll
    for (int i = 1; i < 4; ++i) {
      load_A16(Ms[i], l, h, A1, A2);
      f32x16 D = {};
      D = __builtin_amdgcn_mfma_f32_32x32x16_bf16(A1.s, B1.s, D, 0, 0, 0);
      D = __builtin_amdgcn_mfma_f32_32x32x16_bf16(A2.s, B2.s, D, 0, 0, 0);
#pragma unroll
      for (int r = 0; r < 16; ++r) E2[r] = D[r];
      if (i < 3) repack(E2, h, B1, B2);
    }
    renorm16(E2, Sx);
    unsigned short* qo = Mq16 + (size_t)blockIdx.x * 1024;
#pragma unroll
    for (int r = 0; r < 16; ++r) {
      int row = (r & 3) + 8 * (r >> 2) + 4 * h;
      qo[row * 32 + l] = bf16r(E2[r]);
    }
    if (lane == 0) Sq[blockIdx.x] = Sx;
  }
}

// ------------- K3: per-batch final product + lse + loss ---------------------
__global__ __launch_bounds__(256) void k_tree2(
    const float* __restrict__ outs, const float* __restrict__ trans,
    const unsigned short* __restrict__ Mq16, const float* __restrict__ Sq,
    const float* __restrict__ ws_partial, float* __restrict__ loss)
{
  int tid = threadIdx.x, wave = tid >> 6, lane = tid & 63;
  int l = lane & 31, h = lane >> 5;
  int b = blockIdx.x * 4 + wave;
  const unsigned short* base = Mq16 + (size_t)b * 16384;
  Frag8 A1, A2, B1, B2;
  load_B16(base, l, h, B1, B2);
  float S = 0.f;
#pragma unroll
  for (int q = 0; q < 16; ++q) S += Sq[b * 16 + q];
  float E[16];
  for (int i = 1; i < 16; ++i) {
    load_A16(base + i * 1024, l, h, A1, A2);
    f32x16 D = {};
    D = __builtin_amdgcn_mfma_f32_32x32x16_bf16(A1.s, B1.s, D, 0, 0, 0);
    D = __builtin_amdgcn_mfma_f32_32x32x16_bf16(A2.s, B2.s, D, 0, 0, 0);
#pragma unroll
    for (int r = 0; r < 16; ++r) E[r] = D[r];
    if ((i & 3) == 3) renorm16(E, S);
    if (i < 15) repack(E, h, B1, B2);
  }
  float p0 = (l < NL) ? exp2f(LOG2E * (trans[IDX_BOS * NL + l] + outs[(size_t)b * TT * NL + l])) : 0.f;
  float sum_h = 0.f;
#pragma unroll
  for (int r = 0; r < 16; ++r) {
    float s = bfly_sum32(E[r] * p0);
    int row = (r & 3) + 8 * (r >> 2) + 4 * h;
    float We = (row < NL) ? exp2f(LOG2E * trans[row * NL + IDX_EOS]) : 0.f;
    sum_h += s * We;
  }
  float tot = sum_h + __shfl_xor(sum_h, 32);
  if (lane == 0) {
    float wst = 0.f;
#pragma unroll
    for (int i = 0; i < 8; ++i) wst += ws_partial[b * 8 + i];
    loss[b] = LN2F * (S + log2f(tot)) - wst;
  }
}

extern "C" void kernel_launch(void* const* d_in, const int* in_sizes, int n_in,
                              void* d_out, int out_size, void* d_ws, size_t ws_size,
                              hipStream_t stream) {
  const float* inp   = (const float*)d_in[0];   // (64,512,768) f32
  const int*   tgt   = (const int*)d_in[1];     // (64,512) int
  const float* msk   = (const float*)d_in[2];   // (64,512) f32
  const float* sw    = (const float*)d_in[3];   // (31,768) f32
  const float* sb    = (const float*)d_in[4];   // (31,) f32
  const float* trans = (const float*)d_in[5];   // (31,31) f32

  float* out    = (float*)d_out;
  float* loss   = out;
  float* energy = out + BB;

  // d_ws layout (~6.2 MB used)
  float* outs        = (float*)d_ws;                        // 32768*31 f32
  float* Sq          = outs + (size_t)RTOT * NL;            // 1024
  float* ws_partial  = Sq + 1024;                           // 512
  unsigned short* Mq16 = (unsigned short*)(ws_partial + 512); // 1024*1024 bf16
  unsigned short* Bw   = Mq16 + (size_t)1024 * 1024;          // 32*768 bf16

  k_prep<<<8, 256, 0, stream>>>(sw, Bw);
  k_outs<<<RTOT / 64, 256, 0, stream>>>(inp, Bw, sb, msk, trans, tgt, outs, energy, ws_partial);
  k_seg<<<1024, 256, 0, stream>>>(outs, trans, Mq16, Sq);
  k_tree2<<<16, 256, 0, stream>>>(outs, trans, Mq16, Sq, ws_partial, loss);
}